// Round 1
// baseline (3045.561 us; speedup 1.0000x reference)
//
#include <hip/hip_runtime.h>

#define NN   50000
#define FIN  256
#define C1   64        // HEADS*HID
#define NH   8
#define NHID 8
#define NC   16
#define NE   1600000
#define NTOT (NE + NN)

// workspace offsets (in floats)
#define OFF_H1   0
#define OFF_ALS1 (OFF_H1   + NN*C1)     // 3,200,000
#define OFF_ALD1 (OFF_ALS1 + NN*NH)     // 3,600,000
#define OFF_H2   (OFF_ALD1 + NN*NH)     // 4,000,000
#define OFF_ALS2 (OFF_H2   + NN*NC)     // 4,800,000
#define OFF_ALD2 (OFF_ALS2 + NN)        // 4,850,000
#define OFF_DEN1 (OFF_ALD2 + NN)        // 4,900,000  -- zero region start
#define OFF_ACC1 (OFF_DEN1 + NN*NH)     // 5,300,000
#define OFF_DEN2 (OFF_ACC1 + NN*C1)     // 8,500,000
#define OFF_ACC2 (OFF_DEN2 + NN)        // 8,550,000
#define OFF_END  (OFF_ACC2 + NN*NC)     // 9,350,000
#define ZERO_START OFF_DEN1
#define ZERO_COUNT (OFF_END - OFF_DEN1)

// ---------------- K1: h1 = x @ W1  (50000x256 @ 256x64) ----------------
__global__ __launch_bounds__(256) void k_gemm1(const float* __restrict__ x,
                                               const float* __restrict__ W1,
                                               float* __restrict__ h1) {
    __shared__ float xs[64][68];   // [row][kk], pad for alignment/banks
    __shared__ float ws[64][64];   // [kk][col]
    const int tid = threadIdx.x;
    const int tx = tid & 15, ty = tid >> 4;
    const int r0 = blockIdx.x * 64;
    float acc[4][4] = {};
    for (int k0 = 0; k0 < FIN; k0 += 64) {
        #pragma unroll
        for (int it = 0; it < 4; ++it) {
            int rloc = it * 16 + ty;
            int grow = r0 + rloc;
            float4 v = make_float4(0.f, 0.f, 0.f, 0.f);
            if (grow < NN) v = *(const float4*)(&x[(size_t)grow * FIN + k0 + tx * 4]);
            *(float4*)(&xs[rloc][tx * 4]) = v;
        }
        #pragma unroll
        for (int it = 0; it < 4; ++it) {
            int kk = it * 16 + ty;
            float4 v = *(const float4*)(&W1[(size_t)(k0 + kk) * C1 + tx * 4]);
            *(float4*)(&ws[kk][tx * 4]) = v;
        }
        __syncthreads();
        #pragma unroll 8
        for (int kk = 0; kk < 64; ++kk) {
            float4 wv = *(const float4*)(&ws[kk][tx * 4]);
            #pragma unroll
            for (int m = 0; m < 4; ++m) {
                float xv = xs[m * 16 + ty][kk];
                acc[m][0] += xv * wv.x;
                acc[m][1] += xv * wv.y;
                acc[m][2] += xv * wv.z;
                acc[m][3] += xv * wv.w;
            }
        }
        __syncthreads();
    }
    #pragma unroll
    for (int m = 0; m < 4; ++m) {
        int grow = r0 + m * 16 + ty;
        if (grow < NN) {
            float4 v = make_float4(acc[m][0], acc[m][1], acc[m][2], acc[m][3]);
            *(float4*)(&h1[(size_t)grow * C1 + tx * 4]) = v;
        }
    }
}

// ---------------- K1b: attention logits per (node, head) ----------------
__global__ __launch_bounds__(256) void k_logits1(const float* __restrict__ h1,
                                                 const float* __restrict__ a_src,
                                                 const float* __restrict__ a_dst,
                                                 float* __restrict__ als,
                                                 float* __restrict__ ald) {
    int i = blockIdx.x * 256 + threadIdx.x;   // i = n*8 + head
    if (i >= NN * NH) return;
    int n = i >> 3, hd = i & 7;
    const float4* hp = (const float4*)(&h1[(size_t)n * C1 + hd * NHID]);
    float4 h0 = hp[0], h1v = hp[1];
    const float4* asp = (const float4*)(&a_src[hd * NHID]);
    float4 a0 = asp[0], a1 = asp[1];
    const float4* adp = (const float4*)(&a_dst[hd * NHID]);
    float4 d0 = adp[0], d1 = adp[1];
    float s = h0.x * a0.x + h0.y * a0.y + h0.z * a0.z + h0.w * a0.w
            + h1v.x * a1.x + h1v.y * a1.y + h1v.z * a1.z + h1v.w * a1.w;
    float d = h0.x * d0.x + h0.y * d0.y + h0.z * d0.z + h0.w * d0.w
            + h1v.x * d1.x + h1v.y * d1.y + h1v.z * d1.z + h1v.w * d1.w;
    als[i] = s;
    ald[i] = d;
}

// ---------------- K2: edge pass layer 1 (8 lanes per edge, one per head) --
// softmax without max-subtraction (mathematically identical; |logit| small)
__global__ __launch_bounds__(256) void k_edge1(const int* __restrict__ ei,
                                               const float* __restrict__ h1,
                                               const float* __restrict__ als,
                                               const float* __restrict__ ald,
                                               float* __restrict__ den,
                                               float* __restrict__ acc) {
    int e = blockIdx.x * 32 + (threadIdx.x >> 3);
    int l = threadIdx.x & 7;
    if (e >= NTOT) return;
    int s, d;
    if (e < NE) { s = ei[e]; d = ei[NE + e]; }
    else        { s = e - NE; d = s; }          // self-loop
    float lg = als[s * NH + l] + ald[d * NH + l];
    lg = lg > 0.f ? lg : 0.2f * lg;             // leaky_relu(0.2)
    float ex = __expf(lg);
    atomicAdd(&den[d * NH + l], ex);
    const float4* hp = (const float4*)(&h1[(size_t)s * C1 + l * NHID]);
    float4 a = hp[0], b = hp[1];
    float* ap = &acc[(size_t)d * C1 + l * NHID];
    atomicAdd(ap + 0, ex * a.x);
    atomicAdd(ap + 1, ex * a.y);
    atomicAdd(ap + 2, ex * a.z);
    atomicAdd(ap + 3, ex * a.w);
    atomicAdd(ap + 4, ex * b.x);
    atomicAdd(ap + 5, ex * b.y);
    atomicAdd(ap + 6, ex * b.z);
    atomicAdd(ap + 7, ex * b.w);
}

// ---------------- K3: finalize layer1 (div+bias+ELU) + GEMM2 + logits2 ----
__global__ __launch_bounds__(256) void k_final1(const float* __restrict__ acc1,
                                                const float* __restrict__ den1,
                                                const float* __restrict__ b1,
                                                const float* __restrict__ W2,
                                                const float* __restrict__ as2,
                                                const float* __restrict__ ad2,
                                                float* __restrict__ h2,
                                                float* __restrict__ als2,
                                                float* __restrict__ ald2) {
    __shared__ float w2s[C1][NC];
    __shared__ float hact[16][C1 + 4];
    int tid = threadIdx.x;
    for (int i = tid; i < C1 * NC; i += 256) w2s[i >> 4][i & 15] = W2[i];
    int ln = tid >> 4, j = tid & 15;
    int n = blockIdx.x * 16 + ln;
    if (n < NN) {
        float4 a = *(const float4*)(&acc1[(size_t)n * C1 + j * 4]);
        float dn = den1[n * NH + (j >> 1)];   // channels j*4..j*4+3 share head j>>1
        float o0 = a.x / dn + b1[j * 4 + 0];
        float o1 = a.y / dn + b1[j * 4 + 1];
        float o2 = a.z / dn + b1[j * 4 + 2];
        float o3 = a.w / dn + b1[j * 4 + 3];
        hact[ln][j * 4 + 0] = o0 > 0.f ? o0 : (__expf(o0) - 1.f);
        hact[ln][j * 4 + 1] = o1 > 0.f ? o1 : (__expf(o1) - 1.f);
        hact[ln][j * 4 + 2] = o2 > 0.f ? o2 : (__expf(o2) - 1.f);
        hact[ln][j * 4 + 3] = o3 > 0.f ? o3 : (__expf(o3) - 1.f);
    }
    __syncthreads();
    if (n < NN) {
        float sum = 0.f;
        #pragma unroll
        for (int c = 0; c < C1; ++c) sum += hact[ln][c] * w2s[c][j];
        h2[(size_t)n * NC + j] = sum;
        float ps = sum * as2[j], pd = sum * ad2[j];
        #pragma unroll
        for (int w = 1; w < 16; w <<= 1) {
            ps += __shfl_xor(ps, w);
            pd += __shfl_xor(pd, w);
        }
        if (j == 0) { als2[n] = ps; ald2[n] = pd; }
    }
}

// ---------------- K4: edge pass layer 2 (16 lanes per edge) ----------------
__global__ __launch_bounds__(256) void k_edge2(const int* __restrict__ ei,
                                               const float* __restrict__ h2,
                                               const float* __restrict__ als2,
                                               const float* __restrict__ ald2,
                                               float* __restrict__ den2,
                                               float* __restrict__ acc2) {
    int e = blockIdx.x * 16 + (threadIdx.x >> 4);
    int j = threadIdx.x & 15;
    if (e >= NTOT) return;
    int s, d;
    if (e < NE) { s = ei[e]; d = ei[NE + e]; }
    else        { s = e - NE; d = s; }
    float lg = als2[s] + ald2[d];
    lg = lg > 0.f ? lg : 0.2f * lg;
    float ex = __expf(lg);
    if (j == 0) atomicAdd(&den2[d], ex);
    atomicAdd(&acc2[(size_t)d * NC + j], ex * h2[(size_t)s * NC + j]);
}

// ---------------- K5: finalize layer2 + log_softmax ----------------
__global__ __launch_bounds__(256) void k_final2(const float* __restrict__ acc2,
                                                const float* __restrict__ den2,
                                                const float* __restrict__ b2,
                                                float* __restrict__ out) {
    int i = blockIdx.x * 256 + threadIdx.x;   // i = n*16 + j
    int n = i >> 4, j = i & 15;
    if (n >= NN) return;
    float o = acc2[(size_t)n * NC + j] / den2[n] + b2[j];
    float m = o;
    #pragma unroll
    for (int w = 1; w < 16; w <<= 1) m = fmaxf(m, __shfl_xor(m, w));
    float ex = __expf(o - m);
    float sum = ex;
    #pragma unroll
    for (int w = 1; w < 16; w <<= 1) sum += __shfl_xor(sum, w);
    out[i] = o - m - __logf(sum);
}

extern "C" void kernel_launch(void* const* d_in, const int* in_sizes, int n_in,
                              void* d_out, int out_size, void* d_ws, size_t ws_size,
                              hipStream_t stream) {
    const float* x   = (const float*)d_in[0];
    const int*   ei  = (const int*)  d_in[1];
    const float* W1  = (const float*)d_in[2];
    const float* as1 = (const float*)d_in[3];
    const float* ad1 = (const float*)d_in[4];
    const float* b1  = (const float*)d_in[5];
    const float* W2  = (const float*)d_in[6];
    const float* as2 = (const float*)d_in[7];
    const float* ad2 = (const float*)d_in[8];
    const float* b2  = (const float*)d_in[9];
    float* ws  = (float*)d_ws;
    float* out = (float*)d_out;

    float* h1   = ws + OFF_H1;
    float* als1 = ws + OFF_ALS1;
    float* ald1 = ws + OFF_ALD1;
    float* h2   = ws + OFF_H2;
    float* als2 = ws + OFF_ALS2;
    float* ald2 = ws + OFF_ALD2;
    float* den1 = ws + OFF_DEN1;
    float* acc1 = ws + OFF_ACC1;
    float* den2 = ws + OFF_DEN2;
    float* acc2 = ws + OFF_ACC2;

    // zero accumulators every call (harness poisons ws once, never re-poisons)
    hipMemsetAsync(ws + ZERO_START, 0, (size_t)ZERO_COUNT * sizeof(float), stream);

    k_gemm1 <<<(NN + 63) / 64,          256, 0, stream>>>(x, W1, h1);
    k_logits1<<<(NN * NH + 255) / 256,  256, 0, stream>>>(h1, as1, ad1, als1, ald1);
    k_edge1 <<<(NTOT + 31) / 32,        256, 0, stream>>>(ei, h1, als1, ald1, den1, acc1);
    k_final1<<<(NN + 15) / 16,          256, 0, stream>>>(acc1, den1, b1, W2, as2, ad2, h2, als2, ald2);
    k_edge2 <<<(NTOT + 15) / 16,        256, 0, stream>>>(ei, h2, als2, ald2, den2, acc2);
    k_final2<<<(NN * NC + 255) / 256,   256, 0, stream>>>(acc2, den2, b2, out);
}

// Round 2
// 354.981 us; speedup vs baseline: 8.5795x; 8.5795x over previous
//
#include <hip/hip_runtime.h>

#define NN   50000
#define FIN  256
#define C1   64        // HEADS*HID
#define NH   8
#define NHID 8
#define NC   16
#define NE   1600000
#define NTOT (NE + NN)
#define NBLK_SCAN ((NN + 255) / 256)   // 196

// ---- workspace layout (float-indexed) ----
// region A [0, 3.2M): h1 during layer1; reused for h2/als2/ald2 in layer2
#define OFF_H1   0
#define OFF_H2   0              // reuses h1 space (h1 dead after k_agg1)
#define OFF_ALS2 800000
#define OFF_ALD2 850000
#define OFF_G1   3200000        // ELU'd layer-1 output [NN*C1]
#define OFF_ALS1 6400000
#define OFF_ALD1 6800000
#define OFF_CNT  7200000        // int[50000]
#define OFF_CNT2 7250000        // int[50000]
#define OFF_BSUM 7300000        // int[256]
#define OFF_OFFS 7300256        // int[50001]
#define OFF_SRC  7350272        // int[NTOT]
// end = 9,000,272 floats = 36.0 MB

// ---------------- K1: h1 = x @ W1  (50000x256 @ 256x64) ----------------
__global__ __launch_bounds__(256) void k_gemm1(const float* __restrict__ x,
                                               const float* __restrict__ W1,
                                               float* __restrict__ h1) {
    __shared__ float xs[64][68];
    __shared__ float ws[64][64];
    const int tid = threadIdx.x;
    const int tx = tid & 15, ty = tid >> 4;
    const int r0 = blockIdx.x * 64;
    float acc[4][4] = {};
    for (int k0 = 0; k0 < FIN; k0 += 64) {
        #pragma unroll
        for (int it = 0; it < 4; ++it) {
            int rloc = it * 16 + ty;
            int grow = r0 + rloc;
            float4 v = make_float4(0.f, 0.f, 0.f, 0.f);
            if (grow < NN) v = *(const float4*)(&x[(size_t)grow * FIN + k0 + tx * 4]);
            *(float4*)(&xs[rloc][tx * 4]) = v;
        }
        #pragma unroll
        for (int it = 0; it < 4; ++it) {
            int kk = it * 16 + ty;
            float4 v = *(const float4*)(&W1[(size_t)(k0 + kk) * C1 + tx * 4]);
            *(float4*)(&ws[kk][tx * 4]) = v;
        }
        __syncthreads();
        #pragma unroll 8
        for (int kk = 0; kk < 64; ++kk) {
            float4 wv = *(const float4*)(&ws[kk][tx * 4]);
            #pragma unroll
            for (int m = 0; m < 4; ++m) {
                float xv = xs[m * 16 + ty][kk];
                acc[m][0] += xv * wv.x;
                acc[m][1] += xv * wv.y;
                acc[m][2] += xv * wv.z;
                acc[m][3] += xv * wv.w;
            }
        }
        __syncthreads();
    }
    #pragma unroll
    for (int m = 0; m < 4; ++m) {
        int grow = r0 + m * 16 + ty;
        if (grow < NN) {
            float4 v = make_float4(acc[m][0], acc[m][1], acc[m][2], acc[m][3]);
            *(float4*)(&h1[(size_t)grow * C1 + tx * 4]) = v;
        }
    }
}

// ---------------- K1b: attention logits per (node, head) ----------------
__global__ __launch_bounds__(256) void k_logits1(const float* __restrict__ h1,
                                                 const float* __restrict__ a_src,
                                                 const float* __restrict__ a_dst,
                                                 float* __restrict__ als,
                                                 float* __restrict__ ald) {
    int i = blockIdx.x * 256 + threadIdx.x;   // i = n*8 + head
    if (i >= NN * NH) return;
    int n = i >> 3, hd = i & 7;
    const float4* hp = (const float4*)(&h1[(size_t)n * C1 + hd * NHID]);
    float4 h0 = hp[0], h1v = hp[1];
    const float4* asp = (const float4*)(&a_src[hd * NHID]);
    float4 a0 = asp[0], a1 = asp[1];
    const float4* adp = (const float4*)(&a_dst[hd * NHID]);
    float4 d0 = adp[0], d1 = adp[1];
    float s = h0.x * a0.x + h0.y * a0.y + h0.z * a0.z + h0.w * a0.w
            + h1v.x * a1.x + h1v.y * a1.y + h1v.z * a1.z + h1v.w * a1.w;
    float d = h0.x * d0.x + h0.y * d0.y + h0.z * d0.z + h0.w * d0.w
            + h1v.x * d1.x + h1v.y * d1.y + h1v.z * d1.z + h1v.w * d1.w;
    als[i] = s;
    ald[i] = d;
}

// ---------------- CSR build ----------------
__global__ __launch_bounds__(256) void k_hist(const int* __restrict__ ei,
                                              int* __restrict__ cnt) {
    for (int e = blockIdx.x * 256 + threadIdx.x; e < NTOT; e += gridDim.x * 256) {
        int d = (e < NE) ? ei[NE + e] : (e - NE);
        atomicAdd(&cnt[d], 1);
    }
}

__global__ __launch_bounds__(256) void k_scan1(const int* __restrict__ cnt,
                                               int* __restrict__ bsum) {
    __shared__ int red[256];
    int i = blockIdx.x * 256 + threadIdx.x;
    red[threadIdx.x] = (i < NN) ? cnt[i] : 0;
    __syncthreads();
    for (int s = 128; s > 0; s >>= 1) {
        if (threadIdx.x < s) red[threadIdx.x] += red[threadIdx.x + s];
        __syncthreads();
    }
    if (threadIdx.x == 0) bsum[blockIdx.x] = red[0];
}

__global__ __launch_bounds__(64) void k_scan2(int* __restrict__ bsum,
                                              int* __restrict__ offs) {
    if (threadIdx.x == 0) {
        int run = 0;
        for (int b = 0; b < NBLK_SCAN; ++b) {
            int t = bsum[b];
            bsum[b] = run;
            run += t;
        }
        offs[NN] = NTOT;
    }
}

__global__ __launch_bounds__(256) void k_scan3(const int* __restrict__ cnt,
                                               const int* __restrict__ bsum,
                                               int* __restrict__ offs) {
    __shared__ int sc[256];
    int i = blockIdx.x * 256 + threadIdx.x;
    int v = (i < NN) ? cnt[i] : 0;
    sc[threadIdx.x] = v;
    __syncthreads();
    // Hillis-Steele inclusive scan
    for (int s = 1; s < 256; s <<= 1) {
        int t = (threadIdx.x >= s) ? sc[threadIdx.x - s] : 0;
        __syncthreads();
        sc[threadIdx.x] += t;
        __syncthreads();
    }
    if (i < NN) offs[i] = bsum[blockIdx.x] + sc[threadIdx.x] - v;
}

__global__ __launch_bounds__(256) void k_scatter(const int* __restrict__ ei,
                                                 const int* __restrict__ offs,
                                                 int* __restrict__ cur,
                                                 int* __restrict__ sorted_src) {
    for (int e = blockIdx.x * 256 + threadIdx.x; e < NTOT; e += gridDim.x * 256) {
        int s, d;
        if (e < NE) { s = ei[e]; d = ei[NE + e]; }
        else        { s = e - NE; d = s; }
        int pos = offs[d] + atomicAdd(&cur[d], 1);
        sorted_src[pos] = s;
    }
}

// ---------------- K2: layer-1 aggregation, gather side (no atomics) -------
// one 64-lane wave per dst node; lane c owns channel c, head = c>>3.
// writes normalized + bias + ELU output directly.
__global__ __launch_bounds__(256) void k_agg1(const int* __restrict__ offs,
                                              const int* __restrict__ src,
                                              const float* __restrict__ h1,
                                              const float* __restrict__ als,
                                              const float* __restrict__ ald,
                                              const float* __restrict__ b1,
                                              float* __restrict__ g1) {
    int d = blockIdx.x * 4 + (threadIdx.x >> 6);
    if (d >= NN) return;
    int c = threadIdx.x & 63;
    int h = c >> 3;
    int beg = offs[d], end = offs[d + 1];
    float aldv = ald[d * NH + h];
    float acc = 0.f, den = 0.f;
    int i = beg;
    for (; i + 1 < end; i += 2) {
        int s0 = src[i], s1 = src[i + 1];
        float l0 = als[s0 * NH + h] + aldv;
        float l1 = als[s1 * NH + h] + aldv;
        l0 = l0 > 0.f ? l0 : 0.2f * l0;
        l1 = l1 > 0.f ? l1 : 0.2f * l1;
        float e0 = __expf(l0), e1 = __expf(l1);
        acc += e0 * h1[(size_t)s0 * C1 + c] + e1 * h1[(size_t)s1 * C1 + c];
        den += e0 + e1;
    }
    if (i < end) {
        int s0 = src[i];
        float l0 = als[s0 * NH + h] + aldv;
        l0 = l0 > 0.f ? l0 : 0.2f * l0;
        float e0 = __expf(l0);
        acc += e0 * h1[(size_t)s0 * C1 + c];
        den += e0;
    }
    float o = acc / den + b1[c];
    g1[(size_t)d * C1 + c] = o > 0.f ? o : (__expf(o) - 1.f);
}

// ---------------- K3: GEMM2 (64->16) + layer-2 logits ----------------
__global__ __launch_bounds__(256) void k_gemm2(const float* __restrict__ g1,
                                               const float* __restrict__ W2,
                                               const float* __restrict__ as2,
                                               const float* __restrict__ ad2,
                                               float* __restrict__ h2,
                                               float* __restrict__ als2,
                                               float* __restrict__ ald2) {
    __shared__ float w2s[C1][NC];
    __shared__ float hact[16][C1 + 4];
    int tid = threadIdx.x;
    for (int i = tid; i < C1 * NC; i += 256) w2s[i >> 4][i & 15] = W2[i];
    int ln = tid >> 4, j = tid & 15;
    int n = blockIdx.x * 16 + ln;
    if (n < NN) {
        float4 v = *(const float4*)(&g1[(size_t)n * C1 + j * 4]);
        *(float4*)(&hact[ln][j * 4]) = v;
    }
    __syncthreads();
    if (n < NN) {
        float sum = 0.f;
        #pragma unroll
        for (int c = 0; c < C1; ++c) sum += hact[ln][c] * w2s[c][j];
        h2[(size_t)n * NC + j] = sum;
        float ps = sum * as2[j], pd = sum * ad2[j];
        #pragma unroll
        for (int w = 1; w < 16; w <<= 1) {
            ps += __shfl_xor(ps, w);
            pd += __shfl_xor(pd, w);
        }
        if (j == 0) { als2[n] = ps; ald2[n] = pd; }
    }
}

// ---------------- K4: layer-2 aggregation + log_softmax ----------------
// 16 lanes per dst node.
__global__ __launch_bounds__(256) void k_agg2(const int* __restrict__ offs,
                                              const int* __restrict__ src,
                                              const float* __restrict__ h2,
                                              const float* __restrict__ als2,
                                              const float* __restrict__ ald2,
                                              const float* __restrict__ b2,
                                              float* __restrict__ out) {
    int d = blockIdx.x * 16 + (threadIdx.x >> 4);
    if (d >= NN) return;
    int c = threadIdx.x & 15;
    int beg = offs[d], end = offs[d + 1];
    float aldv = ald2[d];
    float acc = 0.f, den = 0.f;
    int i = beg;
    for (; i + 1 < end; i += 2) {
        int s0 = src[i], s1 = src[i + 1];
        float l0 = als2[s0] + aldv;
        float l1 = als2[s1] + aldv;
        l0 = l0 > 0.f ? l0 : 0.2f * l0;
        l1 = l1 > 0.f ? l1 : 0.2f * l1;
        float e0 = __expf(l0), e1 = __expf(l1);
        acc += e0 * h2[(size_t)s0 * NC + c] + e1 * h2[(size_t)s1 * NC + c];
        den += e0 + e1;
    }
    if (i < end) {
        int s0 = src[i];
        float l0 = als2[s0] + aldv;
        l0 = l0 > 0.f ? l0 : 0.2f * l0;
        float e0 = __expf(l0);
        acc += e0 * h2[(size_t)s0 * NC + c];
        den += e0;
    }
    float o = acc / den + b2[c];
    // fused log_softmax over the 16 class lanes
    float m = o;
    #pragma unroll
    for (int w = 1; w < 16; w <<= 1) m = fmaxf(m, __shfl_xor(m, w));
    float ex = __expf(o - m);
    float sm = ex;
    #pragma unroll
    for (int w = 1; w < 16; w <<= 1) sm += __shfl_xor(sm, w);
    out[(size_t)d * NC + c] = o - m - __logf(sm);
}

extern "C" void kernel_launch(void* const* d_in, const int* in_sizes, int n_in,
                              void* d_out, int out_size, void* d_ws, size_t ws_size,
                              hipStream_t stream) {
    const float* x   = (const float*)d_in[0];
    const int*   ei  = (const int*)  d_in[1];
    const float* W1  = (const float*)d_in[2];
    const float* as1 = (const float*)d_in[3];
    const float* ad1 = (const float*)d_in[4];
    const float* b1  = (const float*)d_in[5];
    const float* W2  = (const float*)d_in[6];
    const float* as2 = (const float*)d_in[7];
    const float* ad2 = (const float*)d_in[8];
    const float* b2  = (const float*)d_in[9];
    float* ws  = (float*)d_ws;
    float* out = (float*)d_out;

    float* h1   = ws + OFF_H1;
    float* g1   = ws + OFF_G1;
    float* als1 = ws + OFF_ALS1;
    float* ald1 = ws + OFF_ALD1;
    float* h2   = ws + OFF_H2;
    float* als2 = ws + OFF_ALS2;
    float* ald2 = ws + OFF_ALD2;
    int* cnt  = (int*)(ws + OFF_CNT);
    int* cur  = (int*)(ws + OFF_CNT2);
    int* bsum = (int*)(ws + OFF_BSUM);
    int* offs = (int*)(ws + OFF_OFFS);
    int* ssrc = (int*)(ws + OFF_SRC);

    // zero the histogram + scatter cursors (400 KB)
    hipMemsetAsync(cnt, 0, (size_t)(2 * NN) * sizeof(int), stream);

    k_gemm1  <<<(NN + 63) / 64,         256, 0, stream>>>(x, W1, h1);
    k_logits1<<<(NN * NH + 255) / 256,  256, 0, stream>>>(h1, as1, ad1, als1, ald1);
    k_hist   <<<2048,                   256, 0, stream>>>(ei, cnt);
    k_scan1  <<<NBLK_SCAN,              256, 0, stream>>>(cnt, bsum);
    k_scan2  <<<1,                       64, 0, stream>>>(bsum, offs);
    k_scan3  <<<NBLK_SCAN,              256, 0, stream>>>(cnt, bsum, offs);
    k_scatter<<<2048,                   256, 0, stream>>>(ei, offs, cur, ssrc);
    k_agg1   <<<(NN + 3) / 4,           256, 0, stream>>>(offs, ssrc, h1, als1, ald1, b1, g1);
    k_gemm2  <<<(NN + 15) / 16,         256, 0, stream>>>(g1, W2, as2, ad2, h2, als2, ald2);
    k_agg2   <<<(NN + 15) / 16,         256, 0, stream>>>(offs, ssrc, h2, als2, ald2, b2, out);
}